// Round 14
// baseline (198.907 us; speedup 1.0000x reference)
//
#include <hip/hip_runtime.h>
#include <hip/hip_bf16.h>

// CRF forward (log-partition) — B=1024, T=512, K=64.
// One sequence per wave; MFMA recurrence with replicated columns (verified
// R10/R12, absmax 8). ONE __expf per step (R12's 16x-redundant exp was the
// issue hog); F distributed through a 2-buffer LDS pipeline:
//   step t: read F(t+1) from wb[par]  ->  8 MFMA  ->  write F(t+2) into
//   wb[par^1]  ->  u = C ∘ F(t)  ->  repack B fragments.
// Single wave per block: DS ops in-order, no barriers.
// R13 lesson: hand-rolled asm global_load + manual s_waitcnt pinning is
// invisible to the compiler's waitcnt pass (asm defs aren't tracked as
// VMEM) -> any RA copy between load and wait reads an in-flight register
// -> NaN. This round: VOLATILE C++ loads for the emission stream — cannot
// sink (R10 bug), real VMEM instrs so every use gets an exact compiler
// vmcnt. No load/wait asm anywhere.

constexpr int CRF_B = 1024;
constexpr int CRF_T = 512;
constexpr int CRF_K = 64;

#define GBIAS 4.5f

typedef short        s8v __attribute__((ext_vector_type(8)));
typedef float        f4v __attribute__((ext_vector_type(4)));
typedef unsigned int u4v __attribute__((ext_vector_type(4)));

__device__ __forceinline__ unsigned short f2bf_rn(float f) { // init-only cvt
    unsigned int u = __float_as_uint(f);
    return (unsigned short)((u + 0x7fffu + ((u >> 16) & 1u)) >> 16);
}
__device__ __forceinline__ unsigned int pkbf(float lo, float hi) {
    unsigned int r;                       // lo16 = bf16(lo), hi16 = bf16(hi)
    asm("v_cvt_pk_bf16_f32 %0, %1, %2" : "=v"(r) : "v"(lo), "v"(hi));
    return r;
}

#define MF(Aop, Bop, Cop) \
    __builtin_amdgcn_mfma_f32_16x16x32_bf16(Aop, Bop, Cop, 0, 0, 0)

// Rebuild B-fragments from f32 state u0..u3 (k-tiles 0..3).
#define PACKB() do {                                                   \
    u4v w0_, w1_;                                                      \
    w0_[0] = pkbf(u0[0], u0[1]);  w0_[1] = pkbf(u0[2], u0[3]);         \
    w0_[2] = pkbf(u1[0], u1[1]);  w0_[3] = pkbf(u1[2], u1[3]);         \
    w1_[0] = pkbf(u2[0], u2[1]);  w1_[1] = pkbf(u2[2], u2[3]);         \
    w1_[2] = pkbf(u3[0], u3[1]);  w1_[3] = pkbf(u3[2], u3[3]);         \
    Bf0 = __builtin_bit_cast(s8v, w0_);                                \
    Bf1 = __builtin_bit_cast(s8v, w1_);                                \
} while (0)

// Rescale: max over this lane's 16 rows + across the 4 gq groups.
#define RESCALE do {                                                   \
    f4v mv_ = __builtin_elementwise_max(                               \
        __builtin_elementwise_max(u0, u1),                             \
        __builtin_elementwise_max(u2, u3));                            \
    float m_ = fmaxf(fmaxf(mv_[0], mv_[1]), fmaxf(mv_[2], mv_[3]));    \
    m_ = fmaxf(m_, __shfl_xor(m_, 16, 64));                            \
    m_ = fmaxf(m_, __shfl_xor(m_, 32, 64));                            \
    float r_ = __builtin_amdgcn_rcpf(m_);                              \
    CC += __logf(m_);                                                  \
    u0 *= r_; u1 *= r_; u2 *= r_; u3 *= r_;                            \
} while (0)

// Emission stream: VOLATILE loads — unsinkable, compiler-exact waits.
#define LOADP(P, tbase) do {                                            \
    P##0 = vfb[(size_t)min((tbase) + 0, lenm1) * CRF_K];                \
    P##1 = vfb[(size_t)min((tbase) + 1, lenm1) * CRF_K];                \
    P##2 = vfb[(size_t)min((tbase) + 2, lenm1) * CRF_K];                \
    P##3 = vfb[(size_t)min((tbase) + 3, lenm1) * CRF_K];                \
} while (0)

// One step t: read FN = F(t+1) from wb[par]; 8 MFMA; write F(t+2) into
// wb[par^1] (one exp, all 64 tags); u = C ∘ FC; repack B. par = (t+1)&1.
#define STEP(pv, par, FC0,FC1,FC2,FC3, FN0,FN1,FN2,FN3, RES) do {       \
    FN0 = *(const f4v*)&wb[par][ 0 + 4 * gq];                           \
    FN1 = *(const f4v*)&wb[par][16 + 4 * gq];                           \
    FN2 = *(const f4v*)&wb[par][32 + 4 * gq];                           \
    FN3 = *(const f4v*)&wb[par][48 + 4 * gq];                           \
    f4v a0 = MF(A00, Bf0, kZ); a0 = MF(A01, Bf1, a0);                   \
    f4v a1 = MF(A10, Bf0, kZ); a1 = MF(A11, Bf1, a1);                   \
    f4v a2 = MF(A20, Bf0, kZ); a2 = MF(A21, Bf1, a2);                   \
    f4v a3 = MF(A30, Bf0, kZ); a3 = MF(A31, Bf1, a3);                   \
    wb[(par) ^ 1][lane] = __expf((pv) - GBIAS);                         \
    u0 = a0 * FC0; u1 = a1 * FC1; u2 = a2 * FC2; u3 = a3 * FC3;         \
    RES;                                                                \
    PACKB();                                                            \
} while (0)

#define STEP_E(pv, RES) STEP(pv, 0, FA0,FA1,FA2,FA3, FB0,FB1,FB2,FB3, RES)
#define STEP_O(pv, RES) STEP(pv, 1, FB0,FB1,FB2,FB3, FA0,FA1,FA2,FA3, RES)

__global__ __launch_bounds__(64)
__attribute__((amdgpu_waves_per_eu(1, 1)))
void crf_forward_kernel(
    const float* __restrict__ feats,      // [B, T, K]
    const float* __restrict__ trans,      // [K, K]
    const int*   __restrict__ seq_lens,   // [B]
    float*       __restrict__ out)        // [B]
{
    const int lane = threadIdx.x;
    const int gq   = lane >> 4;           // k/row sub-index (4-lane group)
    const int c    = lane & 15;           // A row (m) | replicated B/C column
    const int b    = blockIdx.x;          // one sequence per wave

    const f4v kZ = {0.f, 0.f, 0.f, 0.f};

    __shared__ __align__(16) float wb[2][CRF_K];   // F distribution buffers

    // E A-fragments: A(mb,n) reg holds E[16mb + c][32n + kappa(gq,reg)],
    // kappa = 4gq+reg (reg<4) | 16+4gq+(reg-4). Same kappa in PACKB.
    auto ldE = [&](int mb, int n) {
        s8v f;
#pragma unroll
        for (int reg = 0; reg < 8; ++reg) {
            int k = (reg < 4) ? (4 * gq + reg) : (16 + 4 * gq + (reg - 4));
            float v = __expf(trans[(16 * mb + c) * CRF_K + 32 * n + k]);
            f[reg] = (short)f2bf_rn(v);
        }
        return f;
    };
    const s8v A00 = ldE(0, 0), A01 = ldE(0, 1);
    const s8v A10 = ldE(1, 0), A11 = ldE(1, 1);
    const s8v A20 = ldE(2, 0), A21 = ldE(2, 1);
    const s8v A30 = ldE(3, 0), A31 = ldE(3, 1);

    const int lenm1 = seq_lens[b] - 1;    // wave-uniform
    const int L     = lenm1 + 1;

    const float* fbl = feats + (size_t)b * (CRF_T * CRF_K) + 4 * gq;  // init
    const volatile float* vfb =
        feats + (size_t)b * (CRF_T * CRF_K) + lane;                   // stream

    // t = 0: U = exp(emit0 - GBIAS), replicated across columns.
    f4v u0, u1, u2, u3;
    s8v Bf0, Bf1;
    {
        const f4v e0 = *(const f4v*)(fbl);
        const f4v e1 = *(const f4v*)(fbl + 16);
        const f4v e2 = *(const f4v*)(fbl + 32);
        const f4v e3 = *(const f4v*)(fbl + 48);
#pragma unroll
        for (int j = 0; j < 4; ++j) {
            u0[j] = __expf(e0[j] - GBIAS); u1[j] = __expf(e1[j] - GBIAS);
            u2[j] = __expf(e2[j] - GBIAS); u3[j] = __expf(e3[j] - GBIAS);
        }
    }
    float CC = GBIAS;
    PACKB();

    float pa0, pa1, pa2, pa3, pb0, pb1, pb2, pb3;   // emission stream regs
    f4v FA0, FA1, FA2, FA3, FB0, FB1, FB2, FB3;     // distributed F regs

    int t = 1;
    if (lenm1 > 0) {
        // Warmup: F(1) -> wb[1] -> FA; F(2) -> wb[0] (read by step t=1).
        const float p1 = vfb[(size_t)min(1, lenm1) * CRF_K];
        const float p2 = vfb[(size_t)min(2, lenm1) * CRF_K];
        LOADP(pa, 3);                      // p(3..6), in flight
        wb[1][lane] = __expf(p1 - GBIAS);
        wb[0][lane] = __expf(p2 - GBIAS);
        FA0 = *(const f4v*)&wb[1][ 0 + 4 * gq];
        FA1 = *(const f4v*)&wb[1][16 + 4 * gq];
        FA2 = *(const f4v*)&wb[1][32 + 4 * gq];
        FA3 = *(const f4v*)&wb[1][48 + 4 * gq];

        while (t + 8 <= L) {               // full chunks of 8 steps
            LOADP(pb, t + 6);              // p(t+6..t+9), in flight
            STEP_E(pa0, ); STEP_O(pa1, ); STEP_E(pa2, ); STEP_O(pa3, );
            LOADP(pa, t + 10);             // p(t+10..t+13), in flight
            STEP_E(pb0, ); STEP_O(pb1, ); STEP_E(pb2, );
            STEP_O(pb3, RESCALE);
            t += 8;
        }
        const int rem = L - t;             // 0..7 tail steps (uniform)
        if (rem > 0) {
            LOADP(pb, t + 6);              // clamped; extras unused
            /*          */ STEP_E(pa0, );
            if (rem > 1) { STEP_O(pa1, ); }
            if (rem > 2) { STEP_E(pa2, ); }
            if (rem > 3) { STEP_O(pa3, ); }
            if (rem > 4) { STEP_E(pb0, ); }
            if (rem > 5) { STEP_O(pb1, ); }
            if (rem > 6) { STEP_E(pb2, ); }
        }
    }

    // Final LSE: sum this lane's 16 rows + across the 4 gq groups.
    {
        const f4v sv = (u0 + u1) + (u2 + u3);
        float s = (sv[0] + sv[1]) + (sv[2] + sv[3]);
        s += __shfl_xor(s, 16, 64);
        s += __shfl_xor(s, 32, 64);
        const float res = CC + GBIAS * (float)lenm1 + __logf(s);
        if (lane == 0) out[b] = res;
    }
}

extern "C" void kernel_launch(void* const* d_in, const int* in_sizes, int n_in,
                              void* d_out, int out_size, void* d_ws, size_t ws_size,
                              hipStream_t stream)
{
    const float* feats    = (const float*)d_in[0];
    const float* trans    = (const float*)d_in[1];
    const int*   seq_lens = (const int*)d_in[2];
    float*       out      = (float*)d_out;

    crf_forward_kernel<<<dim3(CRF_B), dim3(64), 0, stream>>>(
        feats, trans, seq_lens, out);
}